// Round 10
// baseline (200.732 us; speedup 1.0000x reference)
//
#include <hip/hip_runtime.h>

#define N_NODES 100000
#define N_EDGES 1250000
#define FEATS 64

#define NPB   256                              // nodes per bucket (= blockDim of binB)
#define NBUCK ((N_NODES + NPB - 1) / NPB)      // 391
#define CAP   4096                             // slots/bucket; avg 3197, +16 sigma
#define TILE  2048
#define NTILES ((N_EDGES + TILE - 1) / TILE)   // 611

typedef unsigned short ushort8 __attribute__((ext_vector_type(8)));

__device__ __forceinline__ float bf2f(unsigned short u) {
    return __uint_as_float(((unsigned int)u) << 16);
}
__device__ __forceinline__ unsigned short f2bf(float f) {
    unsigned int x = __float_as_uint(f);
    unsigned int lsb = (x >> 16) & 1u;
    x += 0x7fffu + lsb;                 // round-to-nearest-even
    return (unsigned short)(x >> 16);
}

// ---------------------------------------------------------------------------
// ws layout:
//   cursor [512]            bucket sizes (memset 0; binA atomicAdd, relative)
//   offs   [100004]         CSR row offsets
//   csr_src[1250000]        src ids grouped by dst
//   pairs  int2[391*4096]   bucketed (dst,src) pairs  -- dead after binB
//   h_bf16 = same region as pairs (12.8 MB), written by pack AFTER binB
// total ~18.2 MB (proven available)
// ---------------------------------------------------------------------------

// Pass A: bin edges into 391 coarse buckets by dst>>8. LDS histogram gives
// per-edge local rank; one global atomicAdd per (tile,bucket) reserves a run.
__global__ __launch_bounds__(256) void binA_kernel(
        const int* __restrict__ src,
        const int* __restrict__ dst,
        int* __restrict__ cursor,
        int2* __restrict__ pairs) {
    __shared__ int hist[NBUCK];
    __shared__ int base[NBUCK];
    const int t  = threadIdx.x;
    const int e0 = blockIdx.x * TILE + t * 8;
    const bool full = (blockIdx.x + 1) * TILE <= N_EDGES;

    for (int i = t; i < NBUCK; i += 256) hist[i] = 0;
    __syncthreads();

    int d[8], lr[8];
    if (full) {
        int4 a = *(const int4*)(dst + e0);
        int4 q = *(const int4*)(dst + e0 + 4);
        d[0]=a.x; d[1]=a.y; d[2]=a.z; d[3]=a.w;
        d[4]=q.x; d[5]=q.y; d[6]=q.z; d[7]=q.w;
#pragma unroll
        for (int j = 0; j < 8; ++j) lr[j] = atomicAdd(&hist[d[j] >> 8], 1);
    } else {
#pragma unroll
        for (int j = 0; j < 8; ++j) {
            if (e0 + j < N_EDGES) {
                d[j]  = dst[e0 + j];
                lr[j] = atomicAdd(&hist[d[j] >> 8], 1);
            }
        }
    }
    __syncthreads();

    for (int i = t; i < NBUCK; i += 256)
        base[i] = hist[i] ? atomicAdd(&cursor[i], hist[i]) : 0;   // relative
    __syncthreads();

    if (full) {
        int4 a = *(const int4*)(src + e0);
        int4 q = *(const int4*)(src + e0 + 4);
        int s[8] = {a.x, a.y, a.z, a.w, q.x, q.y, q.z, q.w};
#pragma unroll
        for (int j = 0; j < 8; ++j) {
            int bk  = d[j] >> 8;
            int rel = base[bk] + lr[j];
            if (rel < CAP)                       // overflow guard (never hits)
                pairs[(size_t)bk * CAP + rel] = make_int2(d[j], s[j]);
        }
    } else {
#pragma unroll
        for (int j = 0; j < 8; ++j) {
            if (e0 + j < N_EDGES) {
                int bk  = d[j] >> 8;
                int rel = base[bk] + lr[j];
                if (rel < CAP)
                    pairs[(size_t)bk * CAP + rel] = make_int2(d[j], src[e0 + j]);
            }
        }
    }
}

// Pass B: one block per bucket. eb = sum of earlier bucket sizes (in-block
// reduction). LDS count + scan over 256 local nodes -> coalesced offs slice;
// scatter src into the bucket's contiguous, single-block-owned csr region.
__global__ __launch_bounds__(256) void binB_kernel(
        const int2* __restrict__ pairs,
        const int* __restrict__ cursor,
        int* __restrict__ offs,
        int* __restrict__ csr_src) {
    __shared__ int red[256];
    __shared__ int lcnt[NPB];
    __shared__ int lsum[NPB];
    __shared__ int lcur[NPB];
    const int t = threadIdx.x;
    const int b = blockIdx.x;

    int part = 0;
    for (int i = t; i < b; i += 256) part += cursor[i];
    red[t] = part;
    __syncthreads();
    for (int o = 128; o > 0; o >>= 1) {
        if (t < o) red[t] += red[t + o];
        __syncthreads();
    }
    const int eb   = red[0];
    const int size = cursor[b];
    const int2* bp = pairs + (size_t)b * CAP;

    lcnt[t] = 0;
    __syncthreads();
    for (int i = t; i < size; i += 256) atomicAdd(&lcnt[bp[i].x & (NPB - 1)], 1);
    __syncthreads();

    lsum[t] = lcnt[t];
    __syncthreads();
    for (int off = 1; off < NPB; off <<= 1) {
        int y = (t >= off) ? lsum[t - off] : 0;
        __syncthreads();
        lsum[t] += y;
        __syncthreads();
    }
    const int excl = (t > 0) ? lsum[t - 1] : 0;
    lcur[t] = excl;
    const int node = b * NPB + t;
    if (node < N_NODES) offs[node] = eb + excl;
    if (b == 0 && t == 0) offs[N_NODES] = N_EDGES;
    __syncthreads();

    for (int i = t; i < size; i += 256) {
        int2 p = bp[i];
        int r = atomicAdd(&lcur[p.x & (NPB - 1)], 1);
        csr_src[eb + r] = p.y;
    }
}

// Pack h (fp32) -> h_bf16. 6.4M elems, 8 per thread, exact grid 3125x256.
__global__ __launch_bounds__(256) void pack_kernel(
        const float* __restrict__ h, unsigned short* __restrict__ hb) {
    const int i = (blockIdx.x * 256 + threadIdx.x) * 8;
    float4 a = *(const float4*)(h + i);
    float4 c = *(const float4*)(h + i + 4);
    ushort8 u;
    u[0] = f2bf(a.x); u[1] = f2bf(a.y); u[2] = f2bf(a.z); u[3] = f2bf(a.w);
    u[4] = f2bf(c.x); u[5] = f2bf(c.y); u[6] = f2bf(c.z); u[7] = f2bf(c.w);
    *(ushort8*)(hb + i) = u;
}

// ---------------------------------------------------------------------------
// Fused gather + linear + bias + relu, bf16 h rows (128 B).
// One node per 8-lane GROUP (8 nodes/wave). Each lane loads ushort8 (16 B =
// 8 bf16 feats) -> one full row per group per instruction; unroll x2 -> 16
// independent row-loads in flight per wave. fp32 accumulate in registers.
// ---------------------------------------------------------------------------
__global__ __launch_bounds__(256) void gather_linear_kernel(
        const unsigned short* __restrict__ hb,
        const int* __restrict__ offs,
        const int* __restrict__ csr_src,
        const float* __restrict__ W,    // [o][k] row-major
        const float* __restrict__ b,
        float* __restrict__ out) {
    __shared__ int   sidx[4][8][8];      // [wave][group][slot]
    __shared__ float srow[4][8][FEATS];  // [wave][group][feat]

    const int tid  = threadIdx.x;
    const int lane = tid & 63;
    const int wv   = tid >> 6;
    const int g    = lane >> 3;          // group 0..7
    const int li   = lane & 7;
    const int fo   = li * 8;             // my 8 feats

    float wr[FEATS];
#pragma unroll
    for (int kk = 0; kk < 16; ++kk) {
        float4 w4 = *(const float4*)(W + (size_t)lane * FEATS + kk * 4);
        wr[kk * 4 + 0] = w4.x;
        wr[kk * 4 + 1] = w4.y;
        wr[kk * 4 + 2] = w4.z;
        wr[kk * 4 + 3] = w4.w;
    }
    const float bias = b[lane];

    const int stride = gridDim.x * 32;   // 4 waves * 8 groups per block
    for (int n0 = blockIdx.x * 32 + wv * 8; n0 < N_NODES; n0 += stride) {
        const int n = n0 + g;
        const bool valid = (n < N_NODES);
        const int beg = valid ? offs[n] : 0;
        const int end = valid ? offs[n + 1] : 0;
        const int m   = end - beg;

        float acc0[8], acc1[8];
#pragma unroll
        for (int i = 0; i < 8; ++i) { acc0[i] = 0.f; acc1[i] = 0.f; }

        for (int base = 0; __any(base < m); base += 8) {
            sidx[wv][g][li] = (base + li < m) ? csr_src[beg + base + li] : 0;
            // in-wave DS write->read ordering; no barrier needed
#pragma unroll
            for (int t = 0; t < 8; t += 2) {
                int r0 = sidx[wv][g][t];
                int r1 = sidx[wv][g][t + 1];
                if (base + t < m) {
                    ushort8 u = *(const ushort8*)(hb + (size_t)r0 * FEATS + fo);
#pragma unroll
                    for (int i = 0; i < 8; ++i) acc0[i] += bf2f(u[i]);
                }
                if (base + t + 1 < m) {
                    ushort8 u = *(const ushort8*)(hb + (size_t)r1 * FEATS + fo);
#pragma unroll
                    for (int i = 0; i < 8; ++i) acc1[i] += bf2f(u[i]);
                }
            }
        }
#pragma unroll
        for (int i = 0; i < 8; ++i) acc0[i] += acc1[i];

        *(float4*)&srow[wv][g][fo]     = make_float4(acc0[0], acc0[1], acc0[2], acc0[3]);
        *(float4*)&srow[wv][g][fo + 4] = make_float4(acc0[4], acc0[5], acc0[6], acc0[7]);

        // linear for this wave's 8 nodes; lane = output feature
#pragma unroll
        for (int gg = 0; gg < 8; ++gg) {
            int nn = n0 + gg;
            if (nn >= N_NODES) break;
            const float4* ar = (const float4*)&srow[wv][gg][0];
            float o_acc = bias;
#pragma unroll
            for (int k4 = 0; k4 < 16; ++k4) {
                float4 r = ar[k4];               // b128 broadcast
                o_acc = fmaf(r.x, wr[k4 * 4 + 0], o_acc);
                o_acc = fmaf(r.y, wr[k4 * 4 + 1], o_acc);
                o_acc = fmaf(r.z, wr[k4 * 4 + 2], o_acc);
                o_acc = fmaf(r.w, wr[k4 * 4 + 3], o_acc);
            }
            out[(size_t)nn * FEATS + lane] = fmaxf(o_acc, 0.0f);
        }
    }
}

extern "C" void kernel_launch(void* const* d_in, const int* in_sizes, int n_in,
                              void* d_out, int out_size, void* d_ws, size_t ws_size,
                              hipStream_t stream) {
    const float* h   = (const float*)d_in[0];
    const int*   src = (const int*)d_in[1];
    const int*   dst = (const int*)d_in[2];
    const float* W   = (const float*)d_in[3];
    const float* b   = (const float*)d_in[4];
    float* out = (float*)d_out;

    int*  cursor  = (int*)d_ws;                 // 512
    int*  offs    = cursor + 512;               // 100004
    int*  csr_src = offs + 100004;              // 1250000
    int2* pairs   = (int2*)(csr_src + N_EDGES); // 391*4096 int2 (16B-aligned)
    unsigned short* hb = (unsigned short*)pairs; // reuse after binB (12.8 MB)

    hipMemsetAsync(cursor, 0, 512 * sizeof(int), stream);
    binA_kernel<<<NTILES, 256, 0, stream>>>(src, dst, cursor, pairs);
    binB_kernel<<<NBUCK, 256, 0, stream>>>(pairs, cursor, offs, csr_src);
    pack_kernel<<<3125, 256, 0, stream>>>(h, hb);           // pairs now dead
    gather_linear_kernel<<<3125, 256, 0, stream>>>(hb, offs, csr_src, W, b, out);
}

// Round 11
// 157.313 us; speedup vs baseline: 1.2760x; 1.2760x over previous
//
#include <hip/hip_runtime.h>

#define N_NODES 100000
#define N_EDGES 1250000
#define FEATS 64

#define NPB   128                              // nodes per bucket
#define NBUCK ((N_NODES + NPB - 1) / NPB)      // 782
#define CAP   2304                             // slots/bucket; mean 1600, sd 40 -> +17 sigma
#define TILE  4096
#define NTILES ((N_EDGES + TILE - 1) / TILE)   // 306

typedef unsigned short ushort8 __attribute__((ext_vector_type(8)));

__device__ __forceinline__ float bf2f(unsigned short u) {
    return __uint_as_float(((unsigned int)u) << 16);
}
__device__ __forceinline__ unsigned short f2bf(float f) {
    unsigned int x = __float_as_uint(f);
    unsigned int lsb = (x >> 16) & 1u;
    x += 0x7fffu + lsb;                 // round-to-nearest-even
    return (unsigned short)(x >> 16);
}

// ---------------------------------------------------------------------------
// ws layout:
//   cursor [1024]            bucket sizes (memset 0; binA atomicAdd, relative)
//   pairs  int[782*2304]     packed (src<<7 | dst&127), 7.2 MB
//   hb     ushort[6.4M]      bf16 h copy, 12.8 MB
// total ~20.0 MB (< proven 25.6 MB)
// ---------------------------------------------------------------------------

// Fused: (a) grid-stride pack h -> bf16, (b) bin edges into 782 buckets by
// dst>>7 via LDS histogram + one global atomicAdd per (tile,bucket).
__global__ __launch_bounds__(256) void binA_pack_kernel(
        const float* __restrict__ h,
        unsigned short* __restrict__ hb,
        const int* __restrict__ src,
        const int* __restrict__ dst,
        int* __restrict__ cursor,
        int* __restrict__ pairs) {
    // ---- pack prologue (independent of binning) ----
    const int PTOT = N_NODES * FEATS;           // 6.4M, %8 == 0
    for (int i = (blockIdx.x * 256 + threadIdx.x) * 8; i < PTOT;
         i += gridDim.x * 256 * 8) {
        float4 a = *(const float4*)(h + i);
        float4 c = *(const float4*)(h + i + 4);
        ushort8 u;
        u[0] = f2bf(a.x); u[1] = f2bf(a.y); u[2] = f2bf(a.z); u[3] = f2bf(a.w);
        u[4] = f2bf(c.x); u[5] = f2bf(c.y); u[6] = f2bf(c.z); u[7] = f2bf(c.w);
        *(ushort8*)(hb + i) = u;
    }

    // ---- binning ----
    __shared__ int hist[NBUCK];
    __shared__ int base[NBUCK];
    const int t  = threadIdx.x;
    const int e0 = blockIdx.x * TILE + t * 16;
    const bool full = (blockIdx.x + 1) * TILE <= N_EDGES;

    for (int i = t; i < NBUCK; i += 256) hist[i] = 0;
    __syncthreads();

    int d[16], lr[16];
    if (full) {
#pragma unroll
        for (int q = 0; q < 4; ++q) {
            int4 v = *(const int4*)(dst + e0 + q * 4);
            d[q * 4 + 0] = v.x; d[q * 4 + 1] = v.y;
            d[q * 4 + 2] = v.z; d[q * 4 + 3] = v.w;
        }
#pragma unroll
        for (int j = 0; j < 16; ++j) lr[j] = atomicAdd(&hist[d[j] >> 7], 1);
    } else {
#pragma unroll
        for (int j = 0; j < 16; ++j) {
            if (e0 + j < N_EDGES) {
                d[j]  = dst[e0 + j];
                lr[j] = atomicAdd(&hist[d[j] >> 7], 1);
            }
        }
    }
    __syncthreads();

    for (int i = t; i < NBUCK; i += 256)
        base[i] = hist[i] ? atomicAdd(&cursor[i], hist[i]) : 0;   // relative
    __syncthreads();

    if (full) {
        int s[16];
#pragma unroll
        for (int q = 0; q < 4; ++q) {
            int4 v = *(const int4*)(src + e0 + q * 4);
            s[q * 4 + 0] = v.x; s[q * 4 + 1] = v.y;
            s[q * 4 + 2] = v.z; s[q * 4 + 3] = v.w;
        }
#pragma unroll
        for (int j = 0; j < 16; ++j) {
            int bk  = d[j] >> 7;
            int rel = base[bk] + lr[j];
            if (rel < CAP)                       // overflow guard (never hits)
                pairs[(size_t)bk * CAP + rel] = (s[j] << 7) | (d[j] & (NPB - 1));
        }
    } else {
#pragma unroll
        for (int j = 0; j < 16; ++j) {
            if (e0 + j < N_EDGES) {
                int bk  = d[j] >> 7;
                int rel = base[bk] + lr[j];
                if (rel < CAP)
                    pairs[(size_t)bk * CAP + rel] =
                        (src[e0 + j] << 7) | (d[j] & (NPB - 1));
            }
        }
    }
}

// ---------------------------------------------------------------------------
// One block per 128-node bucket:
//   1. counting sort of the bucket's edges by dst&127 entirely in LDS
//   2. gather: 8-lane group per node, ushort8 (16B) bf16 row loads,
//      fp32 register accumulate (R10's proven shape)
//   3. linear+bias+relu with W rows in VGPRs
// No csr_src / offs global round-trip.
// ---------------------------------------------------------------------------
__global__ __launch_bounds__(256) void agg_kernel(
        const unsigned short* __restrict__ hb,
        const int* __restrict__ pairs,
        const int* __restrict__ cursor,
        const float* __restrict__ W,    // [o][k] row-major
        const float* __restrict__ bias,
        float* __restrict__ out) {
    __shared__ int   ssrc[CAP];          // 9.2 KB sorted src ids
    __shared__ int   lcnt[NPB];
    __shared__ int   loff[NPB + 1];
    __shared__ int   lcur[NPB];
    __shared__ float srow[4][8][FEATS];  // 8 KB

    const int tid  = threadIdx.x;
    const int lane = tid & 63;
    const int wv   = tid >> 6;
    const int g    = lane >> 3;          // group 0..7
    const int li   = lane & 7;
    const int fo   = li * 8;             // my 8 feats

    float wr[FEATS];
#pragma unroll
    for (int kk = 0; kk < 16; ++kk) {
        float4 w4 = *(const float4*)(W + (size_t)lane * FEATS + kk * 4);
        wr[kk * 4 + 0] = w4.x;
        wr[kk * 4 + 1] = w4.y;
        wr[kk * 4 + 2] = w4.z;
        wr[kk * 4 + 3] = w4.w;
    }
    const float bv = bias[lane];

    const int b = blockIdx.x;
    int size = cursor[b];
    if (size > CAP) size = CAP;
    const int* bp = pairs + (size_t)b * CAP;

    // -- counting sort by dst&127 --
    if (tid < NPB) lcnt[tid] = 0;
    __syncthreads();
    for (int i = tid; i < size; i += 256) atomicAdd(&lcnt[bp[i] & (NPB - 1)], 1);
    __syncthreads();
    if (tid < NPB) lcur[tid] = lcnt[tid];      // scan scratch
    __syncthreads();
    for (int off = 1; off < NPB; off <<= 1) {
        int y = 0;
        if (tid < NPB && tid >= off) y = lcur[tid - off];
        __syncthreads();
        if (tid < NPB) lcur[tid] += y;
        __syncthreads();
    }
    if (tid < NPB) loff[tid + 1] = lcur[tid];  // inclusive -> loff[1..128]
    if (tid == 0) loff[0] = 0;
    __syncthreads();
    if (tid < NPB) lcur[tid] = loff[tid];
    __syncthreads();
    for (int i = tid; i < size; i += 256) {
        int p = bp[i];
        int r = atomicAdd(&lcur[p & (NPB - 1)], 1);
        ssrc[r] = p >> 7;
    }
    __syncthreads();

    // -- gather + linear, 4 passes of 32 nodes (4 waves x 8 groups) --
#pragma unroll
    for (int pass = 0; pass < 4; ++pass) {
        const int ln  = pass * 32 + wv * 8 + g;
        const int beg = loff[ln];
        const int m   = loff[ln + 1] - beg;

        float acc0[8], acc1[8];
#pragma unroll
        for (int i = 0; i < 8; ++i) { acc0[i] = 0.f; acc1[i] = 0.f; }

        for (int base = 0; __any(base < m); base += 8) {
#pragma unroll
            for (int t = 0; t < 8; t += 2) {
                const int i0 = base + t, i1 = base + t + 1;
                int r0 = (i0 < m) ? ssrc[beg + i0] : 0;
                int r1 = (i1 < m) ? ssrc[beg + i1] : 0;
                if (i0 < m) {
                    ushort8 u = *(const ushort8*)(hb + (size_t)r0 * FEATS + fo);
#pragma unroll
                    for (int i = 0; i < 8; ++i) acc0[i] += bf2f(u[i]);
                }
                if (i1 < m) {
                    ushort8 u = *(const ushort8*)(hb + (size_t)r1 * FEATS + fo);
#pragma unroll
                    for (int i = 0; i < 8; ++i) acc1[i] += bf2f(u[i]);
                }
            }
        }
#pragma unroll
        for (int i = 0; i < 8; ++i) acc0[i] += acc1[i];

        *(float4*)&srow[wv][g][fo]     = make_float4(acc0[0], acc0[1], acc0[2], acc0[3]);
        *(float4*)&srow[wv][g][fo + 4] = make_float4(acc0[4], acc0[5], acc0[6], acc0[7]);
        // srow is wave-private: in-wave LDS ordering, no barrier needed

        const int n0 = b * NPB + pass * 32 + wv * 8;
#pragma unroll
        for (int gg = 0; gg < 8; ++gg) {
            const int nn = n0 + gg;
            if (nn >= N_NODES) break;
            const float4* ar = (const float4*)&srow[wv][gg][0];
            float o_acc = bv;
#pragma unroll
            for (int k4 = 0; k4 < 16; ++k4) {
                float4 r = ar[k4];               // b128 broadcast
                o_acc = fmaf(r.x, wr[k4 * 4 + 0], o_acc);
                o_acc = fmaf(r.y, wr[k4 * 4 + 1], o_acc);
                o_acc = fmaf(r.z, wr[k4 * 4 + 2], o_acc);
                o_acc = fmaf(r.w, wr[k4 * 4 + 3], o_acc);
            }
            out[(size_t)nn * FEATS + lane] = fmaxf(o_acc, 0.0f);
        }
    }
}

extern "C" void kernel_launch(void* const* d_in, const int* in_sizes, int n_in,
                              void* d_out, int out_size, void* d_ws, size_t ws_size,
                              hipStream_t stream) {
    const float* h   = (const float*)d_in[0];
    const int*   src = (const int*)d_in[1];
    const int*   dst = (const int*)d_in[2];
    const float* W   = (const float*)d_in[3];
    const float* b   = (const float*)d_in[4];
    float* out = (float*)d_out;

    int* cursor = (int*)d_ws;                          // 1024 ints
    int* pairs  = cursor + 1024;                       // 782*2304 = 1.80M ints
    unsigned short* hb = (unsigned short*)(pairs + (size_t)NBUCK * CAP);  // 6.4M

    hipMemsetAsync(cursor, 0, 1024 * sizeof(int), stream);
    binA_pack_kernel<<<NTILES, 256, 0, stream>>>(h, hb, src, dst, cursor, pairs);
    agg_kernel<<<NBUCK, 256, 0, stream>>>(hb, pairs, cursor, W, b, out);
}